// Round 1
// baseline (393.361 us; speedup 1.0000x reference)
//
#include <hip/hip_runtime.h>
#include <math.h>

// Problem constants (from reference): B=4, T=2048, N_EMBD=1024, HEAD=64
#define NE   1024
#define HS   64
#define TT   2048
#define QT   8      // q rows per block in attention
#define KT   64     // k columns per tile

// ---------------------------------------------------------------------------
// Kernel 1: fused QKV projection.  x:[rows,1024] @ W*:[1024,64] + b* -> q/k/v
// Block: 192 threads = 3 waves; wave m handles matrix m (q/k/v), lane = col.
// 8 rows per block staged in LDS; W reads are fully coalesced (64 consecutive
// floats per wave per i).
// ---------------------------------------------------------------------------
__global__ __launch_bounds__(192) void qkv_proj(
    const float* __restrict__ x,
    const float* __restrict__ Wq, const float* __restrict__ bq,
    const float* __restrict__ Wk, const float* __restrict__ bk,
    const float* __restrict__ Wv, const float* __restrict__ bv,
    float* __restrict__ qo, float* __restrict__ ko, float* __restrict__ vo)
{
    __shared__ float xs[8 * NE];   // 32 KB
    const int row0 = blockIdx.x * 8;
    const float* src = x + (size_t)row0 * NE;
    for (int i = threadIdx.x; i < 8 * NE; i += 192) xs[i] = src[i];
    __syncthreads();

    const int m = threadIdx.x >> 6;        // 0=q, 1=k, 2=v
    const int h = threadIdx.x & 63;        // output column
    const float* W    = (m == 0) ? Wq : ((m == 1) ? Wk : Wv);
    const float* bias = (m == 0) ? bq : ((m == 1) ? bk : bv);
    float* out        = (m == 0) ? qo : ((m == 1) ? ko : vo);

    float acc[8] = {0.f, 0.f, 0.f, 0.f, 0.f, 0.f, 0.f, 0.f};
    #pragma unroll 4
    for (int i = 0; i < NE; ++i) {
        const float w = W[i * HS + h];
        #pragma unroll
        for (int r = 0; r < 8; ++r) acc[r] += xs[r * NE + i] * w;
    }
    const float bb = bias[h];
    #pragma unroll
    for (int r = 0; r < 8; ++r)
        out[(size_t)(row0 + r) * HS + h] = acc[r] + bb;
}

// ---------------------------------------------------------------------------
// Kernel 2: causal flash attention, fp32.
// Grid: rows/QT blocks (1024).  Block: 256 threads = 4 waves; wave g owns
// q-rows g*2, g*2+1 of its 8-row tile.  K tile staged transposed in LDS with
// +1 padding (2-way bank aliasing only, which is free).  Online softmax per
// wave via 64-lane butterfly shuffles.  Heavy (large q0) tiles first.
// scores = (q . k) * 8.0   (faithful-to-source scale of sqrt(HEAD))
// ---------------------------------------------------------------------------
__global__ __launch_bounds__(256) void attn(
    const float* __restrict__ q, const float* __restrict__ k,
    const float* __restrict__ v, float* __restrict__ out)
{
    const int nq  = TT / QT;                     // q tiles per batch
    const int b   = blockIdx.x / nq;
    const int qt  = (nq - 1) - (blockIdx.x % nq); // reversed: heavy tiles first
    const int q0  = qt * QT;

    __shared__ float qs[QT * HS];                // 2 KB
    __shared__ float kt[HS * (KT + 1)];          // 16.25 KB, kt[h*(KT+1)+c]
    __shared__ float vs[KT * HS];                // 16 KB
    __shared__ float ps[QT * KT];                // 2 KB

    const int tid  = threadIdx.x;
    const int lane = tid & 63;
    const int wv   = tid >> 6;
    const int r0   = wv * 2;                     // 2 rows per wave

    const float* qb = q + ((size_t)b * TT + q0) * HS;
    const float* kb = k + (size_t)b * TT * HS;
    const float* vb = v + (size_t)b * TT * HS;

    for (int i = tid; i < QT * HS; i += 256) qs[i] = qb[i];

    float m0 = -3.0e38f, m1 = -3.0e38f;
    float l0 = 0.f, l1 = 0.f;
    float a0acc = 0.f, a1acc = 0.f;              // output accumulators

    const int nkt = (q0 + QT + KT - 1) / KT;
    for (int t = 0; t < nkt; ++t) {
        const int j0 = t * KT;
        __syncthreads();   // prior iteration's LDS reads done before overwrite
        for (int e = tid; e < KT * HS; e += 256) {
            const int j = e >> 6, h = e & 63;
            kt[h * (KT + 1) + j] = kb[(size_t)(j0 + j) * HS + h];
            vs[e]                = vb[(size_t)j0 * HS + e];
        }
        __syncthreads();

        // ---- S = 8 * Q K^T ; this thread: column c=lane, rows r0..r0+1 ----
        float s0 = 0.f, s1 = 0.f;
        #pragma unroll 16
        for (int h = 0; h < HS; ++h) {
            const float kv = kt[h * (KT + 1) + lane];
            s0 += qs[(r0 + 0) * HS + h] * kv;
            s1 += qs[(r0 + 1) * HS + h] * kv;
        }
        s0 *= 8.0f; s1 *= 8.0f;

        // causal mask: key index j0+lane must be <= query index q0+row
        if (j0 + lane > q0 + r0 + 0) s0 = -3.0e38f;
        if (j0 + lane > q0 + r0 + 1) s1 = -3.0e38f;

        // ---- online softmax (per wave, rows are wave-private) ----
        float mx0 = s0, mx1 = s1;
        #pragma unroll
        for (int off = 32; off; off >>= 1) {
            mx0 = fmaxf(mx0, __shfl_xor(mx0, off));
            mx1 = fmaxf(mx1, __shfl_xor(mx1, off));
        }
        const float mn0 = fmaxf(m0, mx0), mn1 = fmaxf(m1, mx1);
        const float al0 = __expf(m0 - mn0), al1 = __expf(m1 - mn1);
        const float p0  = __expf(s0 - mn0), p1  = __expf(s1 - mn1);
        float sum0 = p0, sum1 = p1;
        #pragma unroll
        for (int off = 32; off; off >>= 1) {
            sum0 += __shfl_xor(sum0, off);
            sum1 += __shfl_xor(sum1, off);
        }
        l0 = l0 * al0 + sum0;  l1 = l1 * al1 + sum1;
        m0 = mn0;              m1 = mn1;
        a0acc *= al0;          a1acc *= al1;

        ps[(r0 + 0) * KT + lane] = p0;
        ps[(r0 + 1) * KT + lane] = p1;
        // rows r0,r0+1 of ps are written and read only by this wave (in-order
        // DS pipeline per wave) -> no cross-wave barrier needed here.

        // ---- O += P V ; this thread: column h=lane, rows r0..r0+1 ----
        #pragma unroll 8
        for (int j = 0; j < KT; ++j) {
            const float vv = vs[j * HS + lane];
            a0acc += ps[(r0 + 0) * KT + j] * vv;
            a1acc += ps[(r0 + 1) * KT + j] * vv;
        }
    }

    const float inv0 = 1.0f / l0, inv1 = 1.0f / l1;
    out[((size_t)b * TT + q0 + r0 + 0) * HS + lane] = a0acc * inv0;
    out[((size_t)b * TT + q0 + r0 + 1) * HS + lane] = a1acc * inv1;
}

// ---------------------------------------------------------------------------
extern "C" void kernel_launch(void* const* d_in, const int* in_sizes, int n_in,
                              void* d_out, int out_size, void* d_ws, size_t ws_size,
                              hipStream_t stream)
{
    const float* x  = (const float*)d_in[0];
    const float* Wq = (const float*)d_in[1];
    const float* bq = (const float*)d_in[2];
    const float* Wk = (const float*)d_in[3];
    const float* bk = (const float*)d_in[4];
    const float* Wv = (const float*)d_in[5];
    const float* bv = (const float*)d_in[6];
    float* out = (float*)d_out;

    const int rows = in_sizes[0] / NE;           // B*T = 8192
    float* qbuf = (float*)d_ws;
    float* kbuf = qbuf + (size_t)rows * HS;
    float* vbuf = kbuf + (size_t)rows * HS;

    qkv_proj<<<rows / 8, 192, 0, stream>>>(x, Wq, bq, Wk, bk, Wv, bv,
                                           qbuf, kbuf, vbuf);
    attn<<<rows / QT, 256, 0, stream>>>(qbuf, kbuf, vbuf, out);
}

// Round 2
// 156.775 us; speedup vs baseline: 2.5091x; 2.5091x over previous
//
#include <hip/hip_runtime.h>
#include <math.h>

// B=4, T=2048, N_EMBD=1024, HEAD=64. Scores scaled by *sqrt(64)=8 (faithful).
#define NE 1024
#define HS 64
#define TT 2048

typedef __bf16 v8bf __attribute__((ext_vector_type(8)));
typedef float  v4f  __attribute__((ext_vector_type(4)));

#define MFMA(a, b, c) __builtin_amdgcn_mfma_f32_16x16x32_bf16((a), (b), (c), 0, 0, 0)

// ---------------------------------------------------------------------------
// Prep: split Wq|Wk|Wv into transposed hi/lo bf16: wt[n][k], n=0..191
// ---------------------------------------------------------------------------
__global__ __launch_bounds__(256) void prep_w(
    const float* __restrict__ Wq, const float* __restrict__ Wk,
    const float* __restrict__ Wv, __bf16* __restrict__ wth, __bf16* __restrict__ wtl)
{
    int idx = blockIdx.x * 256 + threadIdx.x;      // 192*1024 total
    int n = idx >> 10, k = idx & 1023;
    const float* W = (n < 64) ? Wq : ((n < 128) ? Wk : Wv);
    float w = W[k * HS + (n & 63)];
    __bf16 h = (__bf16)w;
    wth[idx] = h;
    wtl[idx] = (__bf16)(w - (float)h);
}

// ---------------------------------------------------------------------------
// Projection GEMM via split-precision bf16 MFMA.
// Block tile: 64m x 96n, 4 waves (wave w = rows w*16..w*16+15, all 96 cols).
// Epilogue writes: q (scaled x8) hi/lo, k hi/lo [row][64] bf16; v transposed
// per batch: vt[b*64+h][t] bf16.
// ---------------------------------------------------------------------------
#define PSTR 56   // padded LDS row stride (bf16 units); 112B: 16B-aligned, 2-way banks

__global__ __launch_bounds__(256) void proj(
    const float* __restrict__ x, const __bf16* __restrict__ wth,
    const __bf16* __restrict__ wtl,
    const float* __restrict__ bq, const float* __restrict__ bk,
    const float* __restrict__ bv,
    __bf16* __restrict__ qh, __bf16* __restrict__ ql,
    __bf16* __restrict__ kh, __bf16* __restrict__ kl,
    __bf16* __restrict__ vt)
{
    __shared__ __align__(16) __bf16 xsh[64 * PSTR], xsl[64 * PSTR];
    __shared__ __align__(16) __bf16 wsh[96 * PSTR], wsl[96 * PSTR];

    const int m0 = blockIdx.x * 64;
    const int n0 = blockIdx.y * 96;
    const int tid = threadIdx.x, lane = tid & 63, w = tid >> 6;
    const int quad = lane >> 4, l16 = lane & 15;

    v4f acc[6];
    #pragma unroll
    for (int i = 0; i < 6; ++i) acc[i] = (v4f){0.f, 0.f, 0.f, 0.f};

    for (int k0 = 0; k0 < NE; k0 += 32) {
        __syncthreads();
        {   // stage x tile 64x32 fp32 -> hi/lo bf16
            const int r = tid >> 2, cb = (tid & 3) * 8;
            const float* src = x + (size_t)(m0 + r) * NE + k0 + cb;
            float4 f0 = *(const float4*)src;
            float4 f1 = *(const float4*)(src + 4);
            float vals[8] = {f0.x, f0.y, f0.z, f0.w, f1.x, f1.y, f1.z, f1.w};
            __bf16* dh = xsh + r * PSTR + cb;
            __bf16* dl = xsl + r * PSTR + cb;
            #pragma unroll
            for (int i = 0; i < 8; ++i) {
                __bf16 h = (__bf16)vals[i];
                dh[i] = h;
                dl[i] = (__bf16)(vals[i] - (float)h);
            }
        }
        if (tid < 192) {  // stage wt tile 96x32 bf16 (hi & lo), 32B per thread
            const int r = tid >> 1, cb = (tid & 1) * 16;
            const size_t go = (size_t)(n0 + r) * NE + k0 + cb;
            *(float4*)(wsh + r * PSTR + cb)     = *(const float4*)(wth + go);
            *(float4*)(wsh + r * PSTR + cb + 8) = *(const float4*)(wth + go + 8);
            *(float4*)(wsl + r * PSTR + cb)     = *(const float4*)(wtl + go);
            *(float4*)(wsl + r * PSTR + cb + 8) = *(const float4*)(wtl + go + 8);
        }
        __syncthreads();

        v8bf ah = *(const v8bf*)(xsh + (w * 16 + l16) * PSTR + quad * 8);
        v8bf al = *(const v8bf*)(xsl + (w * 16 + l16) * PSTR + quad * 8);
        #pragma unroll
        for (int nt = 0; nt < 6; ++nt) {
            v8bf bh = *(const v8bf*)(wsh + (nt * 16 + l16) * PSTR + quad * 8);
            v8bf bl = *(const v8bf*)(wsl + (nt * 16 + l16) * PSTR + quad * 8);
            acc[nt] = MFMA(ah, bh, acc[nt]);
            acc[nt] = MFMA(ah, bl, acc[nt]);
            acc[nt] = MFMA(al, bh, acc[nt]);
        }
    }

    // epilogue: C layout col=l16(within n-tile), row=quad*4+reg
    #pragma unroll
    for (int nt = 0; nt < 6; ++nt) {
        const int n = n0 + nt * 16 + l16;
        const float bias = (n < 64) ? bq[n] : ((n < 128) ? bk[n - 64] : bv[n - 128]);
        #pragma unroll
        for (int reg = 0; reg < 4; ++reg) {
            const int row = m0 + w * 16 + quad * 4 + reg;
            float v = acc[nt][reg] + bias;
            if (n < 64) {
                float s = v * 8.0f;                  // fold score scale into q
                __bf16 h = (__bf16)s;
                qh[(size_t)row * HS + n] = h;
                ql[(size_t)row * HS + n] = (__bf16)(s - (float)h);
            } else if (n < 128) {
                __bf16 h = (__bf16)v;
                kh[(size_t)row * HS + n - 64] = h;
                kl[(size_t)row * HS + n - 64] = (__bf16)(v - (float)h);
            } else {
                const int b = row >> 11, t = row & 2047, hc = n - 128;
                vt[((size_t)(b * HS + hc)) * TT + t] = (__bf16)v;
            }
        }
    }
}

// ---------------------------------------------------------------------------
// Flash attention, MFMA. Block = 16 q-rows, 4 waves split the key range
// (round-robin 64-key tiles), independent online softmax, merged at the end.
// Fragments straight from global (L2-resident). P via wave-private LDS.
// ---------------------------------------------------------------------------
__global__ __launch_bounds__(256) void attn(
    const __bf16* __restrict__ qh, const __bf16* __restrict__ ql,
    const __bf16* __restrict__ kh, const __bf16* __restrict__ kl,
    const __bf16* __restrict__ vt, float* __restrict__ out)
{
    __shared__ __align__(16) __bf16 ps[4][16 * 72];   // wave-private P, stride 72
    __shared__ float os[4][16 * 68];                  // merged O staging, stride 68
    __shared__ float sm[4][16], sl[4][16];

    const int tid = threadIdx.x, lane = tid & 63, w = tid >> 6;
    const int quad = lane >> 4, l16 = lane & 15;
    const int b = blockIdx.x & 3, qi = blockIdx.x >> 2;
    const int q0 = (127 - qi) * 16;                   // heavy tiles first

    const size_t qrow = ((size_t)b * TT + q0 + l16) * HS;
    const v8bf Qh0 = *(const v8bf*)(qh + qrow + quad * 8);
    const v8bf Qh1 = *(const v8bf*)(qh + qrow + 32 + quad * 8);
    const v8bf Ql0 = *(const v8bf*)(ql + qrow + quad * 8);
    const v8bf Ql1 = *(const v8bf*)(ql + qrow + 32 + quad * 8);

    float mrow[4] = {-3e38f, -3e38f, -3e38f, -3e38f};
    float lrow[4] = {0.f, 0.f, 0.f, 0.f};
    v4f o[4];
    #pragma unroll
    for (int i = 0; i < 4; ++i) o[i] = (v4f){0.f, 0.f, 0.f, 0.f};

    const int irow = q0 + quad * 4;                   // + reg
    const int ntk = (q0 + 16 + 63) >> 6;

    for (int t = w; t < ntk; t += 4) {
        const int j0 = t * 64;
        v4f s[4];
        #pragma unroll
        for (int i = 0; i < 4; ++i) s[i] = (v4f){0.f, 0.f, 0.f, 0.f};

        #pragma unroll
        for (int nt = 0; nt < 4; ++nt) {
            const size_t krow = ((size_t)b * TT + j0 + nt * 16 + l16) * HS;
            v8bf Bh0 = *(const v8bf*)(kh + krow + quad * 8);
            v8bf Bh1 = *(const v8bf*)(kh + krow + 32 + quad * 8);
            v8bf Bl0 = *(const v8bf*)(kl + krow + quad * 8);
            v8bf Bl1 = *(const v8bf*)(kl + krow + 32 + quad * 8);
            s[nt] = MFMA(Qh0, Bh0, s[nt]);
            s[nt] = MFMA(Qh1, Bh1, s[nt]);
            s[nt] = MFMA(Qh0, Bl0, s[nt]);
            s[nt] = MFMA(Qh1, Bl1, s[nt]);
            s[nt] = MFMA(Ql0, Bh0, s[nt]);
            s[nt] = MFMA(Ql1, Bh1, s[nt]);
        }

        // causal mask + row max (rows are per (quad,reg); 16-lane groups share)
        float mx[4] = {-3e38f, -3e38f, -3e38f, -3e38f};
        #pragma unroll
        for (int nt = 0; nt < 4; ++nt)
            #pragma unroll
            for (int reg = 0; reg < 4; ++reg) {
                if (j0 + nt * 16 + l16 > irow + reg) s[nt][reg] = -3e38f;
                mx[reg] = fmaxf(mx[reg], s[nt][reg]);
            }
        #pragma unroll
        for (int off = 8; off; off >>= 1)
            #pragma unroll
            for (int reg = 0; reg < 4; ++reg)
                mx[reg] = fmaxf(mx[reg], __shfl_xor(mx[reg], off));

        float al[4];
        #pragma unroll
        for (int reg = 0; reg < 4; ++reg) {
            float mn = fmaxf(mrow[reg], mx[reg]);
            al[reg] = __expf(mrow[reg] - mn);
            mrow[reg] = mn;
        }
        float rs[4] = {0.f, 0.f, 0.f, 0.f};
        #pragma unroll
        for (int nt = 0; nt < 4; ++nt)
            #pragma unroll
            for (int reg = 0; reg < 4; ++reg) {
                float p = (j0 + nt * 16 + l16 > irow + reg)
                              ? 0.f : __expf(s[nt][reg] - mrow[reg]);
                rs[reg] += p;
                ps[w][(quad * 4 + reg) * 72 + nt * 16 + l16] = (__bf16)p;
            }
        #pragma unroll
        for (int off = 8; off; off >>= 1)
            #pragma unroll
            for (int reg = 0; reg < 4; ++reg)
                rs[reg] += __shfl_xor(rs[reg], off);
        #pragma unroll
        for (int reg = 0; reg < 4; ++reg)
            lrow[reg] = lrow[reg] * al[reg] + rs[reg];
        #pragma unroll
        for (int nt = 0; nt < 4; ++nt)
            #pragma unroll
            for (int reg = 0; reg < 4; ++reg)
                o[nt][reg] *= al[reg];

        // PV: A = P (wave-private LDS, no barrier needed), B = V^T from global
        v8bf Pa0 = *(const v8bf*)(&ps[w][l16 * 72 + quad * 8]);
        v8bf Pa1 = *(const v8bf*)(&ps[w][l16 * 72 + 32 + quad * 8]);
        #pragma unroll
        for (int nt = 0; nt < 4; ++nt) {
            const size_t vrow = ((size_t)(b * HS + nt * 16 + l16)) * TT + j0;
            v8bf Vb0 = *(const v8bf*)(vt + vrow + quad * 8);
            v8bf Vb1 = *(const v8bf*)(vt + vrow + 32 + quad * 8);
            o[nt] = MFMA(Pa0, Vb0, o[nt]);
            o[nt] = MFMA(Pa1, Vb1, o[nt]);
        }
    }

    // merge the 4 key-split waves
    if (l16 == 0) {
        #pragma unroll
        for (int reg = 0; reg < 4; ++reg) {
            sm[w][quad * 4 + reg] = mrow[reg];
            sl[w][quad * 4 + reg] = lrow[reg];
        }
    }
    __syncthreads();
    float sc[4];
    #pragma unroll
    for (int reg = 0; reg < 4; ++reg) {
        const int r = quad * 4 + reg;
        float M = fmaxf(fmaxf(sm[0][r], sm[1][r]), fmaxf(sm[2][r], sm[3][r]));
        sc[reg] = __expf(mrow[reg] - M);
    }
    #pragma unroll
    for (int nt = 0; nt < 4; ++nt)
        #pragma unroll
        for (int reg = 0; reg < 4; ++reg)
            os[w][(quad * 4 + reg) * 68 + nt * 16 + l16] = o[nt][reg] * sc[reg];
    __syncthreads();

    #pragma unroll
    for (int k = 0; k < 4; ++k) {
        const int m = w * 4 + k;
        float M = fmaxf(fmaxf(sm[0][m], sm[1][m]), fmaxf(sm[2][m], sm[3][m]));
        float L = sl[0][m] * __expf(sm[0][m] - M) + sl[1][m] * __expf(sm[1][m] - M)
                + sl[2][m] * __expf(sm[2][m] - M) + sl[3][m] * __expf(sm[3][m] - M);
        float val = os[0][m * 68 + lane] + os[1][m * 68 + lane]
                  + os[2][m * 68 + lane] + os[3][m * 68 + lane];
        out[((size_t)b * TT + q0 + m) * HS + lane] = val / L;
    }
}

// ---------------------------------------------------------------------------
extern "C" void kernel_launch(void* const* d_in, const int* in_sizes, int n_in,
                              void* d_out, int out_size, void* d_ws, size_t ws_size,
                              hipStream_t stream)
{
    const float* x  = (const float*)d_in[0];
    const float* Wq = (const float*)d_in[1];
    const float* bq = (const float*)d_in[2];
    const float* Wk = (const float*)d_in[3];
    const float* bk = (const float*)d_in[4];
    const float* Wv = (const float*)d_in[5];
    const float* bv = (const float*)d_in[6];
    float* out = (float*)d_out;

    const int rows = in_sizes[0] / NE;   // 8192
    char* p = (char*)d_ws;
    __bf16* wth = (__bf16*)p;                 p += (size_t)192 * NE * 2;
    __bf16* wtl = (__bf16*)p;                 p += (size_t)192 * NE * 2;
    __bf16* qhb = (__bf16*)p;                 p += (size_t)rows * HS * 2;
    __bf16* qlb = (__bf16*)p;                 p += (size_t)rows * HS * 2;
    __bf16* khb = (__bf16*)p;                 p += (size_t)rows * HS * 2;
    __bf16* klb = (__bf16*)p;                 p += (size_t)rows * HS * 2;
    __bf16* vtb = (__bf16*)p;                 p += (size_t)rows * HS * 2;

    prep_w<<<(192 * NE) / 256, 256, 0, stream>>>(Wq, Wk, Wv, wth, wtl);
    proj<<<dim3(rows / 64, 2), 256, 0, stream>>>(x, wth, wtl, bq, bk, bv,
                                                 qhb, qlb, khb, klb, vtb);
    attn<<<(rows / 16), 256, 0, stream>>>(qhb, qlb, khb, klb, vtb, out);
}